// Round 2
// baseline (499.001 us; speedup 1.0000x reference)
//
#include <hip/hip_runtime.h>

typedef _Float16 f16x8 __attribute__((ext_vector_type(8)));
typedef float f32x4 __attribute__((ext_vector_type(4)));

#define EXP_CLIP 10.0f
#define FEPS 1e-6f
#define WSCALE 16384.0f      // 2^14 weight prescale (kills fp16-denorm weights)
#define WDESCALE (1.0f/16384.0f)
#define PSCALE 1024.0f       // proj weight prescale
#define PDESCALE (1.0f/1024.0f)

__device__ __forceinline__ _Float16 cvh(float v) {
  v = fminf(fmaxf(v, -60000.f), 60000.f);
  return (_Float16)v;
}

__device__ __forceinline__ void gload_lds16(const void* g, void* l) {
  __builtin_amdgcn_global_load_lds(
      (const __attribute__((address_space(1))) void*)g,
      (__attribute__((address_space(3))) void*)l, 16, 0, 0);
}

// ---------------------------------------------------------------------------
// Prep: per (layer, j) block, 512 threads over i.
// Wh[j][(k-1)*512+i] = fp16( softmax(alphas[i,j,:])[k] * scale[i,j,k] * 2^14 )
// Wl = fp16 residual (EMIT_LO only). biasvec[j] = sum_i sum_{k>=1} w*bias (unscaled).
// ---------------------------------------------------------------------------
template <bool EMIT_LO>
__global__ __launch_bounds__(512)
void prep_weights(const float* __restrict__ alphas, const float* __restrict__ scale,
                  const float* __restrict__ bias, _Float16* __restrict__ Wh,
                  _Float16* __restrict__ Wl, float* __restrict__ biasvec) {
  int j = blockIdx.x;   // 0..511
  int i = threadIdx.x;  // 0..511
  size_t base = ((size_t)i * 512 + j) * 8;
  float a[8];
#pragma unroll
  for (int k = 0; k < 8; ++k) a[k] = alphas[base + k];
  float m = a[0];
#pragma unroll
  for (int k = 1; k < 8; ++k) m = fmaxf(m, a[k]);
  float e[8], sum = 0.f;
#pragma unroll
  for (int k = 0; k < 8; ++k) { e[k] = __expf(a[k] - m); sum += e[k]; }
  float inv = 1.f / sum;
  float bp = 0.f;
#pragma unroll
  for (int k = 1; k < 8; ++k) {
    float w = e[k] * inv;
    float ws = fminf(fmaxf(w * scale[base + k] * WSCALE, -60000.f), 60000.f);
    _Float16 wh = (_Float16)ws;
    size_t o = (size_t)j * 3584 + (size_t)(k - 1) * 512 + i;
    Wh[o] = wh;
    if (EMIT_LO) Wl[o] = (_Float16)(ws - (float)wh);
    bp += w * bias[base + k];
  }
  __shared__ float red[512];
  red[i] = bp;
  __syncthreads();
  for (int off = 256; off > 0; off >>= 1) {
    if (i < off) red[i] += red[i + off];
    __syncthreads();
  }
  if (i == 0) biasvec[j] = red[0];
}

// ---------------------------------------------------------------------------
// Featurize (layer-2 input): h [rows][512] fp32 -> out [rows][3584] fp16
// ---------------------------------------------------------------------------
__global__ __launch_bounds__(256)
void featurize_k(const float* __restrict__ in, _Float16* __restrict__ out, int total) {
  int idx = blockIdx.x * 256 + threadIdx.x;
  if (idx >= total) return;
  int b = idx >> 9, i = idx & 511;
  float x = in[idx];
  float x2 = x * x, x3 = x2 * x;
  float ex = __expf(fminf(fmaxf(x, -EXP_CLIP), EXP_CLIP));
  float ln = __logf(fabsf(x) + FEPS);
  float rc = x / (x2 + FEPS);
  float sn = __sinf(x);
  _Float16* o = out + (size_t)b * 3584 + i;
  o[0]    = cvh(x);
  o[512]  = cvh(x2);
  o[1024] = cvh(x3);
  o[1536] = cvh(ex);
  o[2048] = cvh(ln);
  o[2560] = cvh(rc);
  o[3072] = cvh(sn);
}

__global__ __launch_bounds__(256)
void cvt_half_k(const float* __restrict__ in, _Float16* __restrict__ out, int n) {
  int idx = blockIdx.x * 256 + threadIdx.x;
  if (idx < n) out[idx] = (_Float16)(in[idx] * PSCALE);
}

// ---------------------------------------------------------------------------
// Layer-1 fused GEMM: H[16384][512] = feats(X) @ (Wh+Wl)^T * 2^-14 + biasvec
// Split-fp16 3-term MFMA (hi*hi + lo*hi + hi*lo) => ~fp32-accurate h.
// Features computed on the fly from X (L3-resident), written hi/lo to LDS.
// ---------------------------------------------------------------------------
__global__ __launch_bounds__(256, 2)
void gemm_l1(const float* __restrict__ X, const _Float16* __restrict__ Wh,
             const _Float16* __restrict__ Wl, const float* __restrict__ bias,
             float* __restrict__ H) {
  __shared__ __align__(16) _Float16 Ah[128][64];
  __shared__ __align__(16) _Float16 Al[128][64];
  __shared__ __align__(16) _Float16 Bh[128][64];
  __shared__ __align__(16) _Float16 Bl[128][64];
  const int K = 3584;
  int lin = blockIdx.x;           // 512 blocks
  int wg = (lin & 7) * 64 + (lin >> 3);
  int bn = wg & 3, bm = wg >> 2;
  int row0 = bm * 128, col0 = bn * 128;
  int tid = threadIdx.x, lane = tid & 63, wave = tid >> 6;
  int wm = wave >> 1, wn = wave & 1;
  int l16 = lane & 15, lh = lane >> 4;
  int sr = lane >> 3, sc = (lane & 7) * 8;
  int ar = tid >> 3;              // 0..31
  int ac = (tid & 7) * 8;         // 0..56

  f32x4 acc[4][4];
#pragma unroll
  for (int m = 0; m < 4; ++m)
#pragma unroll
    for (int n = 0; n < 4; ++n) acc[m][n] = (f32x4){0.f, 0.f, 0.f, 0.f};

#pragma unroll 1
  for (int kk0 = 0; kk0 < K; kk0 += 64) {
    int kp = kk0 >> 9;            // primitive 0..6
    int i0 = kk0 & 511;
    // ---- stage B (weights hi+lo) via global_load_lds ----
    const _Float16* Bgh = Wh + (size_t)col0 * K + kk0;
    const _Float16* Bgl = Wl + (size_t)col0 * K + kk0;
#pragma unroll
    for (int it = 0; it < 4; ++it) {
      int chunk = it * 4 + wave;
      int r = chunk * 8 + sr;
      gload_lds16(Bgh + (size_t)r * K + sc, (_Float16*)&Bh[0][0] + chunk * 512);
      gload_lds16(Bgl + (size_t)r * K + sc, (_Float16*)&Bl[0][0] + chunk * 512);
    }
    // ---- stage A: featurize x tile, split hi/lo ----
#pragma unroll
    for (int it = 0; it < 4; ++it) {
      int r = it * 32 + ar;
      const float* xp = X + (size_t)(row0 + r) * 512 + i0 + ac;
      float4 x01 = *(const float4*)xp;
      float4 x23 = *(const float4*)(xp + 4);
      float xv[8] = {x01.x, x01.y, x01.z, x01.w, x23.x, x23.y, x23.z, x23.w};
      f16x8 hv, lv;
#pragma unroll
      for (int e = 0; e < 8; ++e) {
        float x = xv[e], f;
        switch (kp) {
          case 0: f = x; break;
          case 1: f = x * x; break;
          case 2: f = x * x * x; break;
          case 3: f = __expf(fminf(fmaxf(x, -EXP_CLIP), EXP_CLIP)); break;
          case 4: f = __logf(fabsf(x) + FEPS); break;
          case 5: f = x / (x * x + FEPS); break;
          default: f = __sinf(x); break;
        }
        _Float16 fh = (_Float16)f;
        hv[e] = fh;
        lv[e] = (_Float16)(f - (float)fh);
      }
      *(f16x8*)&Ah[r][ac] = hv;
      *(f16x8*)&Al[r][ac] = lv;
    }
    __syncthreads();
    // ---- 3-term MFMA ----
#pragma unroll
    for (int kc = 0; kc < 2; ++kc) {
      f16x8 ah[4], al[4];
#pragma unroll
      for (int m = 0; m < 4; ++m) {
        ah[m] = *(const f16x8*)&Ah[wm * 64 + m * 16 + l16][kc * 32 + lh * 8];
        al[m] = *(const f16x8*)&Al[wm * 64 + m * 16 + l16][kc * 32 + lh * 8];
      }
#pragma unroll
      for (int n = 0; n < 4; ++n) {
        f16x8 bh = *(const f16x8*)&Bh[wn * 64 + n * 16 + l16][kc * 32 + lh * 8];
        f16x8 bl = *(const f16x8*)&Bl[wn * 64 + n * 16 + l16][kc * 32 + lh * 8];
#pragma unroll
        for (int m = 0; m < 4; ++m) {
          acc[m][n] = __builtin_amdgcn_mfma_f32_16x16x32_f16(ah[m], bh, acc[m][n], 0, 0, 0);
          acc[m][n] = __builtin_amdgcn_mfma_f32_16x16x32_f16(al[m], bh, acc[m][n], 0, 0, 0);
          acc[m][n] = __builtin_amdgcn_mfma_f32_16x16x32_f16(ah[m], bl, acc[m][n], 0, 0, 0);
        }
      }
    }
    __syncthreads();
  }

#pragma unroll
  for (int m = 0; m < 4; ++m) {
    int row = row0 + wm * 64 + m * 16 + lh * 4;
#pragma unroll
    for (int n = 0; n < 4; ++n) {
      int col = col0 + wn * 64 + n * 16 + l16;
      float bv = bias[col];
#pragma unroll
      for (int r = 0; r < 4; ++r)
        H[(size_t)(row + r) * 512 + col] = acc[m][n][r] * WDESCALE + bv;
    }
  }
}

// ---------------------------------------------------------------------------
// Plain fp16 GEMM: C[M][N] = A[M][K] * BT[N][K]^T * outscale + bias[N]
// ---------------------------------------------------------------------------
template <bool OUT_HALF>
__global__ __launch_bounds__(256)
void gemm_tn(const _Float16* __restrict__ A, const _Float16* __restrict__ BT,
             const float* __restrict__ bias, void* __restrict__ C,
             int M, int N, int K, int nbn_log2, int nwg, float outscale) {
  __shared__ __align__(16) _Float16 Ash[128][64];
  __shared__ __align__(16) _Float16 Bsh[128][64];
  int lin = blockIdx.x;
  int q = nwg >> 3;
  int wg = (lin & 7) * q + (lin >> 3);
  int bn = wg & ((1 << nbn_log2) - 1);
  int bm = wg >> nbn_log2;
  int row0 = bm * 128, col0 = bn * 128;
  int tid = threadIdx.x, lane = tid & 63, wave = tid >> 6;
  int wm = wave >> 1, wn = wave & 1;
  int l16 = lane & 15, lh = lane >> 4;
  int sr = lane >> 3, sc = (lane & 7) * 8;

  f32x4 acc[4][4];
#pragma unroll
  for (int m = 0; m < 4; ++m)
#pragma unroll
    for (int n = 0; n < 4; ++n) acc[m][n] = (f32x4){0.f, 0.f, 0.f, 0.f};

  for (int kk0 = 0; kk0 < K; kk0 += 64) {
    const _Float16* Ag = A + (size_t)row0 * K + kk0;
    const _Float16* Bg = BT + (size_t)col0 * K + kk0;
#pragma unroll
    for (int it = 0; it < 4; ++it) {
      int chunk = it * 4 + wave;
      int r = chunk * 8 + sr;
      gload_lds16(Ag + (size_t)r * K + sc, (_Float16*)&Ash[0][0] + chunk * 512);
      gload_lds16(Bg + (size_t)r * K + sc, (_Float16*)&Bsh[0][0] + chunk * 512);
    }
    __syncthreads();
#pragma unroll
    for (int kc = 0; kc < 2; ++kc) {
      f16x8 af[4], bf[4];
#pragma unroll
      for (int m = 0; m < 4; ++m)
        af[m] = *(const f16x8*)&Ash[wm * 64 + m * 16 + l16][kc * 32 + lh * 8];
#pragma unroll
      for (int n = 0; n < 4; ++n)
        bf[n] = *(const f16x8*)&Bsh[wn * 64 + n * 16 + l16][kc * 32 + lh * 8];
#pragma unroll
      for (int m = 0; m < 4; ++m)
#pragma unroll
        for (int n = 0; n < 4; ++n)
          acc[m][n] = __builtin_amdgcn_mfma_f32_16x16x32_f16(af[m], bf[n], acc[m][n], 0, 0, 0);
    }
    __syncthreads();
  }

#pragma unroll
  for (int m = 0; m < 4; ++m) {
    int row = row0 + wm * 64 + m * 16 + lh * 4;
#pragma unroll
    for (int n = 0; n < 4; ++n) {
      int col = col0 + wn * 64 + n * 16 + l16;
      float bv = bias[col];
#pragma unroll
      for (int r = 0; r < 4; ++r) {
        float v = acc[m][n][r] * outscale + bv;
        if (OUT_HALF)
          ((_Float16*)C)[(size_t)(row + r) * N + col] = cvh(v);
        else
          ((float*)C)[(size_t)(row + r) * N + col] = v;
      }
    }
  }
}

// ---------------------------------------------------------------------------
extern "C" void kernel_launch(void* const* d_in, const int* in_sizes, int n_in,
                              void* d_out, int out_size, void* d_ws, size_t ws_size,
                              hipStream_t stream) {
  const float* x  = (const float*)d_in[0];
  const float* a0 = (const float*)d_in[1];
  const float* s0 = (const float*)d_in[2];
  const float* b0 = (const float*)d_in[3];
  const float* a1 = (const float*)d_in[4];
  const float* s1 = (const float*)d_in[5];
  const float* b1 = (const float*)d_in[6];
  const float* W  = (const float*)d_in[7];
  const float* bb = (const float*)d_in[8];

  const int Bn = 16384, D = 512, KK = 3584, DOUT = 256;

  char* p = (char*)d_ws;
  _Float16* Afeat = (_Float16*)p;                 // [16384][3584] fp16 (layer-2 feats)
  _Float16* Wh0   = (_Float16*)p;                 // aliased: dead once gemm_l1 done
  _Float16* Wl0   = (_Float16*)(p + 3670016);
  p += (size_t)Bn * KK * 2;                       // 117,440,512
  float*    h     = (float*)p;                    // fp32 h; later ghalf (fp16)
  _Float16* ghalf = (_Float16*)p;
  p += (size_t)Bn * D * 4;                        // 33,554,432
  _Float16* Wh1   = (_Float16*)p; p += (size_t)D * KK * 2;   // 3,670,016
  _Float16* WpT   = (_Float16*)p; p += (size_t)DOUT * D * 2; // 262,144
  float*    biasv = (float*)p;    p += 2 * D * 4;            // 4,096

  prep_weights<true ><<<dim3(512), dim3(512), 0, stream>>>(a0, s0, b0, Wh0, Wl0, biasv);
  prep_weights<false><<<dim3(512), dim3(512), 0, stream>>>(a1, s1, b1, Wh1, nullptr, biasv + 512);
  cvt_half_k<<<dim3(512), dim3(256), 0, stream>>>(W, WpT, DOUT * D);

  // layer 1: fused featurize + split-fp16 GEMM -> h (fp32, ~exact)
  gemm_l1<<<dim3(512), dim3(256), 0, stream>>>(x, Wh0, Wl0, biasv, h);

  // layer 2: featurize h -> fp16, plain fp16 GEMM -> g (fp16)
  featurize_k<<<dim3(Bn * D / 256), dim3(256), 0, stream>>>(h, Afeat, Bn * D);
  gemm_tn<true><<<dim3(512), dim3(256), 0, stream>>>(Afeat, Wh1, biasv + 512, ghalf,
                                                     Bn, D, KK, 2, 512, WDESCALE);

  // projection
  gemm_tn<false><<<dim3(256), dim3(256), 0, stream>>>(ghalf, WpT, bb, (float*)d_out,
                                                      Bn, DOUT, D, 1, 256, PDESCALE);
}

// Round 3
// 450.801 us; speedup vs baseline: 1.1069x; 1.1069x over previous
//
#include <hip/hip_runtime.h>

typedef _Float16 f16x8 __attribute__((ext_vector_type(8)));
typedef float f32x4 __attribute__((ext_vector_type(4)));

#define EXP_CLIP 10.0f
#define FEPS 1e-6f
#define WSCALE 16384.0f      // 2^14 weight prescale (kills fp16-denorm weights)
#define WDESCALE (1.0f/16384.0f)
#define PSCALE 1024.0f       // proj weight prescale
#define PDESCALE (1.0f/1024.0f)

__device__ __forceinline__ _Float16 cvh(float v) {
  v = fminf(fmaxf(v, -60000.f), 60000.f);
  return (_Float16)v;
}

__device__ __forceinline__ void gload_lds16(const void* g, void* l) {
  __builtin_amdgcn_global_load_lds(
      (const __attribute__((address_space(1))) void*)g,
      (__attribute__((address_space(3))) void*)l, 16, 0, 0);
}

// XOR-swizzled LDS offset (half units) for a [*][64]-half tile.
// byte ^= ((row&7)<<4)  <=>  half ^= ((row&7)<<3). 16B alignment preserved.
__device__ __forceinline__ int swz(int row, int colh) {
  return row * 64 + (colh ^ ((row & 7) << 3));
}

// ---------------------------------------------------------------------------
// Prep: per (layer, j) block, 512 threads over i.
// Wh[j][(k-1)*512+i] = fp16( softmax(alphas[i,j,:])[k] * scale[i,j,k] * 2^14 )
// Wl = fp16 residual (EMIT_LO only). biasvec[j] = sum_i sum_{k>=1} w*bias.
// ---------------------------------------------------------------------------
template <bool EMIT_LO>
__global__ __launch_bounds__(512)
void prep_weights(const float* __restrict__ alphas, const float* __restrict__ scale,
                  const float* __restrict__ bias, _Float16* __restrict__ Wh,
                  _Float16* __restrict__ Wl, float* __restrict__ biasvec) {
  int j = blockIdx.x;   // 0..511
  int i = threadIdx.x;  // 0..511
  size_t base = ((size_t)i * 512 + j) * 8;
  float a[8];
#pragma unroll
  for (int k = 0; k < 8; ++k) a[k] = alphas[base + k];
  float m = a[0];
#pragma unroll
  for (int k = 1; k < 8; ++k) m = fmaxf(m, a[k]);
  float e[8], sum = 0.f;
#pragma unroll
  for (int k = 0; k < 8; ++k) { e[k] = __expf(a[k] - m); sum += e[k]; }
  float inv = 1.f / sum;
  float bp = 0.f;
#pragma unroll
  for (int k = 1; k < 8; ++k) {
    float w = e[k] * inv;
    float ws = fminf(fmaxf(w * scale[base + k] * WSCALE, -60000.f), 60000.f);
    _Float16 wh = (_Float16)ws;
    size_t o = (size_t)j * 3584 + (size_t)(k - 1) * 512 + i;
    Wh[o] = wh;
    if (EMIT_LO) Wl[o] = (_Float16)(ws - (float)wh);
    bp += w * bias[base + k];
  }
  __shared__ float red[512];
  red[i] = bp;
  __syncthreads();
  for (int off = 256; off > 0; off >>= 1) {
    if (i < off) red[i] += red[i + off];
    __syncthreads();
  }
  if (i == 0) biasvec[j] = red[0];
}

// ---------------------------------------------------------------------------
// Featurize (layer-2 input): h [rows][512] fp32 -> out [rows][3584] fp16
// ---------------------------------------------------------------------------
__global__ __launch_bounds__(256)
void featurize_k(const float* __restrict__ in, _Float16* __restrict__ out, int total) {
  int idx = blockIdx.x * 256 + threadIdx.x;
  if (idx >= total) return;
  int b = idx >> 9, i = idx & 511;
  float x = in[idx];
  float x2 = x * x, x3 = x2 * x;
  float ex = __expf(fminf(fmaxf(x, -EXP_CLIP), EXP_CLIP));
  float ln = __logf(fabsf(x) + FEPS);
  float rc = x / (x2 + FEPS);
  float sn = __sinf(x);
  _Float16* o = out + (size_t)b * 3584 + i;
  o[0]    = cvh(x);
  o[512]  = cvh(x2);
  o[1024] = cvh(x3);
  o[1536] = cvh(ex);
  o[2048] = cvh(ln);
  o[2560] = cvh(rc);
  o[3072] = cvh(sn);
}

__global__ __launch_bounds__(256)
void cvt_half_k(const float* __restrict__ in, _Float16* __restrict__ out, int n) {
  int idx = blockIdx.x * 256 + threadIdx.x;
  if (idx < n) out[idx] = (_Float16)(in[idx] * PSCALE);
}

// ---------------------------------------------------------------------------
// Layer-1 fused GEMM: H[16384][512] = feats(X) @ (Wh+Wl)^T * 2^-14 + biasvec
// Split-fp16 3-term MFMA (hi*hi + lo*hi + hi*lo) => ~fp32-accurate h.
// LDS tiles XOR-swizzled (T2): B via pre-swizzled global source col (rule #21),
// A via swizzled ds_write. Reads use swz() on both.
// ---------------------------------------------------------------------------
__global__ __launch_bounds__(256, 2)
void gemm_l1(const float* __restrict__ X, const _Float16* __restrict__ Wh,
             const _Float16* __restrict__ Wl, const float* __restrict__ bias,
             float* __restrict__ H) {
  __shared__ __align__(16) _Float16 Ah[128 * 64];
  __shared__ __align__(16) _Float16 Al[128 * 64];
  __shared__ __align__(16) _Float16 Bh[128 * 64];
  __shared__ __align__(16) _Float16 Bl[128 * 64];
  const int K = 3584;
  int lin = blockIdx.x;           // 512 blocks
  int wg = (lin & 7) * 64 + (lin >> 3);
  int bn = wg & 3, bm = wg >> 2;
  int row0 = bm * 128, col0 = bn * 128;
  int tid = threadIdx.x, lane = tid & 63, wave = tid >> 6;
  int wm = wave >> 1, wn = wave & 1;
  int l16 = lane & 15, lh = lane >> 4;
  int sr = lane >> 3;                          // row within 8-row chunk
  int sc = ((lane & 7) * 8) ^ (sr << 3);       // PRE-SWIZZLED source col (halves)
  int ar = tid >> 3;              // 0..31
  int ac = (tid & 7) * 8;         // 0..56

  f32x4 acc[4][4];
#pragma unroll
  for (int m = 0; m < 4; ++m)
#pragma unroll
    for (int n = 0; n < 4; ++n) acc[m][n] = (f32x4){0.f, 0.f, 0.f, 0.f};

#pragma unroll 1
  for (int kk0 = 0; kk0 < K; kk0 += 64) {
    int kp = kk0 >> 9;            // primitive 0..6
    int i0 = kk0 & 511;
    // ---- stage B (weights hi+lo) via global_load_lds, source pre-swizzled ----
    const _Float16* Bgh = Wh + (size_t)col0 * K + kk0;
    const _Float16* Bgl = Wl + (size_t)col0 * K + kk0;
#pragma unroll
    for (int it = 0; it < 4; ++it) {
      int chunk = it * 4 + wave;
      int r = chunk * 8 + sr;
      gload_lds16(Bgh + (size_t)r * K + sc, Bh + chunk * 512);
      gload_lds16(Bgl + (size_t)r * K + sc, Bl + chunk * 512);
    }
    // ---- stage A: featurize x tile, split hi/lo, swizzled ds_write ----
#pragma unroll
    for (int it = 0; it < 4; ++it) {
      int r = it * 32 + ar;
      const float* xp = X + (size_t)(row0 + r) * 512 + i0 + ac;
      float4 x01 = *(const float4*)xp;
      float4 x23 = *(const float4*)(xp + 4);
      float xv[8] = {x01.x, x01.y, x01.z, x01.w, x23.x, x23.y, x23.z, x23.w};
      f16x8 hv, lv;
#pragma unroll
      for (int e = 0; e < 8; ++e) {
        float x = xv[e], f;
        switch (kp) {
          case 0: f = x; break;
          case 1: f = x * x; break;
          case 2: f = x * x * x; break;
          case 3: f = __expf(fminf(fmaxf(x, -EXP_CLIP), EXP_CLIP)); break;
          case 4: f = __logf(fabsf(x) + FEPS); break;
          case 5: f = x / (x * x + FEPS); break;
          default: f = __sinf(x); break;
        }
        _Float16 fh = (_Float16)f;
        hv[e] = fh;
        lv[e] = (_Float16)(f - (float)fh);
      }
      int wo = swz(r, ac);
      *(f16x8*)&Ah[wo] = hv;
      *(f16x8*)&Al[wo] = lv;
    }
    __syncthreads();
    // ---- 3-term MFMA, swizzled fragment reads ----
#pragma unroll
    for (int kc = 0; kc < 2; ++kc) {
      f16x8 ah[4], al[4];
#pragma unroll
      for (int m = 0; m < 4; ++m) {
        int off = swz(wm * 64 + m * 16 + l16, kc * 32 + lh * 8);
        ah[m] = *(const f16x8*)&Ah[off];
        al[m] = *(const f16x8*)&Al[off];
      }
#pragma unroll
      for (int n = 0; n < 4; ++n) {
        int off = swz(wn * 64 + n * 16 + l16, kc * 32 + lh * 8);
        f16x8 bh = *(const f16x8*)&Bh[off];
        f16x8 bl = *(const f16x8*)&Bl[off];
#pragma unroll
        for (int m = 0; m < 4; ++m) {
          acc[m][n] = __builtin_amdgcn_mfma_f32_16x16x32_f16(ah[m], bh, acc[m][n], 0, 0, 0);
          acc[m][n] = __builtin_amdgcn_mfma_f32_16x16x32_f16(al[m], bh, acc[m][n], 0, 0, 0);
          acc[m][n] = __builtin_amdgcn_mfma_f32_16x16x32_f16(ah[m], bl, acc[m][n], 0, 0, 0);
        }
      }
    }
    __syncthreads();
  }

#pragma unroll
  for (int m = 0; m < 4; ++m) {
    int row = row0 + wm * 64 + m * 16 + lh * 4;
#pragma unroll
    for (int n = 0; n < 4; ++n) {
      int col = col0 + wn * 64 + n * 16 + l16;
      float bv = bias[col];
#pragma unroll
      for (int r = 0; r < 4; ++r)
        H[(size_t)(row + r) * 512 + col] = acc[m][n][r] * WDESCALE + bv;
    }
  }
}

// ---------------------------------------------------------------------------
// Plain fp16 GEMM: C[M][N] = A[M][K] * BT[N][K]^T * outscale + bias[N]
// Both tiles staged via gload_lds with pre-swizzled source; swizzled reads.
// ---------------------------------------------------------------------------
template <bool OUT_HALF>
__global__ __launch_bounds__(256)
void gemm_tn(const _Float16* __restrict__ A, const _Float16* __restrict__ BT,
             const float* __restrict__ bias, void* __restrict__ C,
             int M, int N, int K, int nbn_log2, int nwg, float outscale) {
  __shared__ __align__(16) _Float16 Ash[128 * 64];
  __shared__ __align__(16) _Float16 Bsh[128 * 64];
  int lin = blockIdx.x;
  int q = nwg >> 3;
  int wg = (lin & 7) * q + (lin >> 3);
  int bn = wg & ((1 << nbn_log2) - 1);
  int bm = wg >> nbn_log2;
  int row0 = bm * 128, col0 = bn * 128;
  int tid = threadIdx.x, lane = tid & 63, wave = tid >> 6;
  int wm = wave >> 1, wn = wave & 1;
  int l16 = lane & 15, lh = lane >> 4;
  int sr = lane >> 3;
  int sc = ((lane & 7) * 8) ^ (sr << 3);       // pre-swizzled source col (halves)

  f32x4 acc[4][4];
#pragma unroll
  for (int m = 0; m < 4; ++m)
#pragma unroll
    for (int n = 0; n < 4; ++n) acc[m][n] = (f32x4){0.f, 0.f, 0.f, 0.f};

  for (int kk0 = 0; kk0 < K; kk0 += 64) {
    const _Float16* Ag = A + (size_t)row0 * K + kk0;
    const _Float16* Bg = BT + (size_t)col0 * K + kk0;
#pragma unroll
    for (int it = 0; it < 4; ++it) {
      int chunk = it * 4 + wave;
      int r = chunk * 8 + sr;
      gload_lds16(Ag + (size_t)r * K + sc, Ash + chunk * 512);
      gload_lds16(Bg + (size_t)r * K + sc, Bsh + chunk * 512);
    }
    __syncthreads();
#pragma unroll
    for (int kc = 0; kc < 2; ++kc) {
      f16x8 af[4], bf[4];
#pragma unroll
      for (int m = 0; m < 4; ++m)
        af[m] = *(const f16x8*)&Ash[swz(wm * 64 + m * 16 + l16, kc * 32 + lh * 8)];
#pragma unroll
      for (int n = 0; n < 4; ++n)
        bf[n] = *(const f16x8*)&Bsh[swz(wn * 64 + n * 16 + l16, kc * 32 + lh * 8)];
#pragma unroll
      for (int m = 0; m < 4; ++m)
#pragma unroll
        for (int n = 0; n < 4; ++n)
          acc[m][n] = __builtin_amdgcn_mfma_f32_16x16x32_f16(af[m], bf[n], acc[m][n], 0, 0, 0);
    }
    __syncthreads();
  }

#pragma unroll
  for (int m = 0; m < 4; ++m) {
    int row = row0 + wm * 64 + m * 16 + lh * 4;
#pragma unroll
    for (int n = 0; n < 4; ++n) {
      int col = col0 + wn * 64 + n * 16 + l16;
      float bv = bias[col];
#pragma unroll
      for (int r = 0; r < 4; ++r) {
        float v = acc[m][n][r] * outscale + bv;
        if (OUT_HALF)
          ((_Float16*)C)[(size_t)(row + r) * N + col] = cvh(v);
        else
          ((float*)C)[(size_t)(row + r) * N + col] = v;
      }
    }
  }
}

// ---------------------------------------------------------------------------
extern "C" void kernel_launch(void* const* d_in, const int* in_sizes, int n_in,
                              void* d_out, int out_size, void* d_ws, size_t ws_size,
                              hipStream_t stream) {
  const float* x  = (const float*)d_in[0];
  const float* a0 = (const float*)d_in[1];
  const float* s0 = (const float*)d_in[2];
  const float* b0 = (const float*)d_in[3];
  const float* a1 = (const float*)d_in[4];
  const float* s1 = (const float*)d_in[5];
  const float* b1 = (const float*)d_in[6];
  const float* W  = (const float*)d_in[7];
  const float* bb = (const float*)d_in[8];

  const int Bn = 16384, D = 512, KK = 3584, DOUT = 256;

  char* p = (char*)d_ws;
  _Float16* Afeat = (_Float16*)p;                 // [16384][3584] fp16 (layer-2 feats)
  _Float16* Wh0   = (_Float16*)p;                 // aliased: dead once gemm_l1 done
  _Float16* Wl0   = (_Float16*)(p + 3670016);
  p += (size_t)Bn * KK * 2;                       // 117,440,512
  float*    h     = (float*)p;                    // fp32 h; later ghalf (fp16)
  _Float16* ghalf = (_Float16*)p;
  p += (size_t)Bn * D * 4;                        // 33,554,432
  _Float16* Wh1   = (_Float16*)p; p += (size_t)D * KK * 2;   // 3,670,016
  _Float16* WpT   = (_Float16*)p; p += (size_t)DOUT * D * 2; // 262,144
  float*    biasv = (float*)p;    p += 2 * D * 4;            // 4,096

  prep_weights<true ><<<dim3(512), dim3(512), 0, stream>>>(a0, s0, b0, Wh0, Wl0, biasv);
  prep_weights<false><<<dim3(512), dim3(512), 0, stream>>>(a1, s1, b1, Wh1, nullptr, biasv + 512);
  cvt_half_k<<<dim3(512), dim3(256), 0, stream>>>(W, WpT, DOUT * D);

  // layer 1: fused featurize + split-fp16 GEMM -> h (fp32, ~exact)
  gemm_l1<<<dim3(512), dim3(256), 0, stream>>>(x, Wh0, Wl0, biasv, h);

  // layer 2: featurize h -> fp16, plain fp16 GEMM -> g (fp16)
  featurize_k<<<dim3(Bn * D / 256), dim3(256), 0, stream>>>(h, Afeat, Bn * D);
  gemm_tn<true><<<dim3(512), dim3(256), 0, stream>>>(Afeat, Wh1, biasv + 512, ghalf,
                                                     Bn, D, KK, 2, 512, WDESCALE);

  // projection
  gemm_tn<false><<<dim3(256), dim3(256), 0, stream>>>(ghalf, WpT, bb, (float*)d_out,
                                                      Bn, DOUT, D, 1, 256, PDESCALE);
}